// Round 1
// baseline (1689.768 us; speedup 1.0000x reference)
//
#include <hip/hip_runtime.h>

#define NN 20000
#define NE 150000
#define CC 512
#define KW 8

// ---------------- setup kernels ----------------

__global__ __launch_bounds__(256) void k_zero(int* __restrict__ deg, int* __restrict__ cursor) {
  int i = blockIdx.x * blockDim.x + threadIdx.x;
  if (i < NN) { deg[i] = 0; cursor[i] = 0; }
}

__global__ __launch_bounds__(256) void k_count(const int* __restrict__ row, int* __restrict__ deg) {
  int e = blockIdx.x * blockDim.x + threadIdx.x;
  if (e < NE) atomicAdd(&deg[row[e]], 1);
}

__global__ __launch_bounds__(256) void k_dinv(const int* __restrict__ deg, float* __restrict__ dinv) {
  int i = blockIdx.x * blockDim.x + threadIdx.x;
  if (i < NN) {
    int d = deg[i];
    dinv[i] = (d > 0) ? rsqrtf((float)d) : 0.0f;
  }
}

// single-block exclusive scan of deg[0..NN) -> row_off
__global__ __launch_bounds__(1024) void k_scan(const int* __restrict__ deg, int* __restrict__ row_off) {
  __shared__ int sm[1024];
  __shared__ int running;
  const int tid = threadIdx.x;
  if (tid == 0) running = 0;
  __syncthreads();
  for (int base = 0; base < NN; base += 1024) {
    int i = base + tid;
    int v = (i < NN) ? deg[i] : 0;
    sm[tid] = v;
    __syncthreads();
    for (int off = 1; off < 1024; off <<= 1) {
      int t = (tid >= off) ? sm[tid - off] : 0;
      __syncthreads();
      if (tid >= off) sm[tid] += t;
      __syncthreads();
    }
    int excl = sm[tid] - v;
    int run0 = running;
    if (i < NN) row_off[i] = run0 + excl;
    __syncthreads();
    if (tid == 0) running = run0 + sm[1023];
    __syncthreads();
  }
  if (tid == 0) row_off[NN] = NE;
}

__global__ __launch_bounds__(256) void k_fill(const int* __restrict__ row, const int* __restrict__ col,
    const int* __restrict__ row_off, int* __restrict__ cursor, const float* __restrict__ dinv,
    int* __restrict__ csr_col, float* __restrict__ csr_val) {
  int e = blockIdx.x * blockDim.x + threadIdx.x;
  if (e < NE) {
    int r = row[e], c = col[e];
    int pos = row_off[r] + atomicAdd(&cursor[r], 1);
    csr_col[pos] = c;
    csr_val[pos] = -dinv[r] * dinv[c];
  }
}

// ---------------- SPMM: dst[i] = alpha * sum_e val*src[col] + beta * prev[i] ----------------
// one block per node, 128 threads * 4 channels = 512
// in-place safe when dst == prev (each element read once then written by same thread)

__global__ __launch_bounds__(128) void k_spmm(const float* __restrict__ src,
    const float* __restrict__ prev, float* __restrict__ dst,
    const int* __restrict__ row_off, const int* __restrict__ csr_col,
    const float* __restrict__ csr_val, float alpha, float beta)
{
  const int i = blockIdx.x;
  const int c = threadIdx.x * 4;
  const int e0 = row_off[i];
  const int e1 = row_off[i + 1];
  float4 acc = make_float4(0.f, 0.f, 0.f, 0.f);
  for (int e = e0; e < e1; ++e) {
    int j = csr_col[e];
    float v = csr_val[e];
    const float4 xv = *(const float4*)&src[(size_t)j * CC + c];
    acc.x += v * xv.x; acc.y += v * xv.y; acc.z += v * xv.z; acc.w += v * xv.w;
  }
  float4 r;
  if (beta != 0.0f) {
    const float4 p = *(const float4*)&prev[(size_t)i * CC + c];
    r.x = alpha * acc.x + beta * p.x;
    r.y = alpha * acc.y + beta * p.y;
    r.z = alpha * acc.z + beta * p.z;
    r.w = alpha * acc.w + beta * p.w;
  } else {
    r.x = alpha * acc.x; r.y = alpha * acc.y; r.z = alpha * acc.z; r.w = alpha * acc.w;
  }
  *(float4*)&dst[(size_t)i * CC + c] = r;
}

// ---------------- GEMM: C (+)= A[M,512] @ W[512,512]  (f32 vector ALU) ----------------
// 128x128 block tile, BK=16, 256 threads, 8x8 microtile, float4 LDS/global access.

__global__ __launch_bounds__(256) void k_gemm(const float* __restrict__ A,
    const float* __restrict__ W, float* __restrict__ C,
    const float* __restrict__ bias, int first)
{
  __shared__ float As[16][128];   // As[k][m]
  __shared__ float Bs[16][128];   // Bs[k][n]
  const int tid = threadIdx.x;
  const int tx = tid & 15;
  const int ty = tid >> 4;
  const int m0 = blockIdx.y * 128;
  const int n0 = blockIdx.x * 128;

  float acc[8][8];
  #pragma unroll
  for (int i = 0; i < 8; ++i)
    #pragma unroll
    for (int j = 0; j < 8; ++j) acc[i][j] = 0.0f;

  for (int k0 = 0; k0 < CC; k0 += 16) {
    // stage A tile (transposed into As[k][m])
    #pragma unroll
    for (int i = 0; i < 2; ++i) {
      int f = tid + i * 256;       // 512 float4s
      int r = f >> 2;              // 0..127 tile row
      int kq = f & 3;              // which float4 along k
      int gm = m0 + r;
      float4 v = make_float4(0.f, 0.f, 0.f, 0.f);
      if (gm < NN) v = *(const float4*)&A[(size_t)gm * CC + k0 + kq * 4];
      As[kq * 4 + 0][r] = v.x;
      As[kq * 4 + 1][r] = v.y;
      As[kq * 4 + 2][r] = v.z;
      As[kq * 4 + 3][r] = v.w;
    }
    // stage B tile (natural layout)
    #pragma unroll
    for (int i = 0; i < 2; ++i) {
      int f = tid + i * 256;       // 512 float4s
      int r = f >> 5;              // 0..15 k row
      int nq = f & 31;             // float4 along n
      *(float4*)&Bs[r][nq * 4] = *(const float4*)&W[(size_t)(k0 + r) * CC + n0 + nq * 4];
    }
    __syncthreads();

    #pragma unroll
    for (int kk = 0; kk < 16; ++kk) {
      float a[8], b[8];
      *(float4*)(a + 0) = *(const float4*)&As[kk][ty * 4];
      *(float4*)(a + 4) = *(const float4*)&As[kk][64 + ty * 4];
      *(float4*)(b + 0) = *(const float4*)&Bs[kk][tx * 4];
      *(float4*)(b + 4) = *(const float4*)&Bs[kk][64 + tx * 4];
      #pragma unroll
      for (int i = 0; i < 8; ++i)
        #pragma unroll
        for (int j = 0; j < 8; ++j)
          acc[i][j] += a[i] * b[j];
    }
    __syncthreads();
  }

  #pragma unroll
  for (int i = 0; i < 8; ++i) {
    int gm = m0 + ((i < 4) ? (ty * 4 + i) : (64 + ty * 4 + (i - 4)));
    if (gm >= NN) continue;
    #pragma unroll
    for (int jc = 0; jc < 2; ++jc) {
      int gn = n0 + jc * 64 + tx * 4;
      float4 r;
      r.x = acc[i][jc * 4 + 0];
      r.y = acc[i][jc * 4 + 1];
      r.z = acc[i][jc * 4 + 2];
      r.w = acc[i][jc * 4 + 3];
      float* p = &C[(size_t)gm * CC + gn];
      if (first) {
        const float4 bb = *(const float4*)&bias[gn];
        r.x += bb.x; r.y += bb.y; r.z += bb.z; r.w += bb.w;
        *(float4*)p = r;
      } else {
        const float4 o = *(const float4*)p;
        r.x += o.x; r.y += o.y; r.z += o.z; r.w += o.w;
        *(float4*)p = r;
      }
    }
  }
}

// ---------------- launch ----------------

extern "C" void kernel_launch(void* const* d_in, const int* in_sizes, int n_in,
                              void* d_out, int out_size, void* d_ws, size_t ws_size,
                              hipStream_t stream) {
  const float* x      = (const float*)d_in[0];
  const int*   row    = (const int*)d_in[1];
  const int*   col    = row + NE;
  const float* weight = (const float*)d_in[2];
  const float* bias   = (const float*)d_in[3];
  float* out = (float*)d_out;

  // workspace layout (~83.5 MB)
  float* TxA     = (float*)d_ws;
  float* TxB     = TxA + (size_t)NN * CC;
  float* dinv    = TxB + (size_t)NN * CC;
  float* csr_val = dinv + NN;
  int*   deg     = (int*)(csr_val + NE);
  int*   cursor  = deg + NN;
  int*   row_off = cursor + NN;
  int*   csr_col = row_off + NN + 1;

  k_zero<<<(NN + 255) / 256, 256, 0, stream>>>(deg, cursor);
  k_count<<<(NE + 255) / 256, 256, 0, stream>>>(row, deg);
  k_dinv<<<(NN + 255) / 256, 256, 0, stream>>>(deg, dinv);
  k_scan<<<1, 1024, 0, stream>>>(deg, row_off);
  k_fill<<<(NE + 255) / 256, 256, 0, stream>>>(row, col, row_off, cursor, dinv, csr_col, csr_val);

  dim3 gg(CC / 128, (NN + 127) / 128);

  // out = x @ W0 + bias
  k_gemm<<<gg, 256, 0, stream>>>(x, weight, out, bias, 1);

  // Tx1 = spmm(x)
  k_spmm<<<NN, 128, 0, stream>>>(x, x, TxA, row_off, csr_col, csr_val, 1.0f, 0.0f);
  k_gemm<<<gg, 256, 0, stream>>>(TxA, weight + (size_t)1 * CC * CC, out, bias, 0);

  // Tx2 = 2*spmm(Tx1) - x
  k_spmm<<<NN, 128, 0, stream>>>(TxA, x, TxB, row_off, csr_col, csr_val, 2.0f, -1.0f);
  k_gemm<<<gg, 256, 0, stream>>>(TxB, weight + (size_t)2 * CC * CC, out, bias, 0);

  // k = 3..7:  Tx_k = 2*spmm(Tx_{k-1}) - Tx_{k-2}, ping-pong in place
  float* bufs[2] = { TxA, TxB };
  for (int k = 3; k < KW; ++k) {
    float* dst = bufs[(k + 1) & 1];  // holds Tx_{k-2}, overwritten with Tx_k
    float* src = bufs[k & 1];        // holds Tx_{k-1}
    k_spmm<<<NN, 128, 0, stream>>>(src, dst, dst, row_off, csr_col, csr_val, 2.0f, -1.0f);
    k_gemm<<<gg, 256, 0, stream>>>(dst, weight + (size_t)k * CC * CC, out, bias, 0);
  }
}

// Round 2
// 790.202 us; speedup vs baseline: 2.1384x; 2.1384x over previous
//
#include <hip/hip_runtime.h>

#define NN 20000
#define NP 20096   // M padded to multiple of 128 for GEMM staging
#define NE 150000
#define CC 512
#define KW 8

typedef __attribute__((ext_vector_type(8))) short short8;
typedef __attribute__((ext_vector_type(4))) float f32x4;
typedef __attribute__((ext_vector_type(4))) unsigned short ushort4v;
typedef __attribute__((ext_vector_type(8))) unsigned short ushort8v;

__device__ inline unsigned short f2bf(float f) {   // RNE f32->bf16
  unsigned u = __builtin_bit_cast(unsigned, f);
  u += 0x7fffu + ((u >> 16) & 1u);
  return (unsigned short)(u >> 16);
}

__device__ inline void gload_lds16(const void* g, void* l) {
  __builtin_amdgcn_global_load_lds(
      (const __attribute__((address_space(1))) unsigned int*)g,
      (__attribute__((address_space(3))) unsigned int*)l, 16, 0, 0);
}

// ---------------- setup kernels ----------------

__global__ __launch_bounds__(256) void k_zero(int* __restrict__ deg, int* __restrict__ cursor) {
  int i = blockIdx.x * blockDim.x + threadIdx.x;
  if (i < NN) { deg[i] = 0; cursor[i] = 0; }
}

__global__ __launch_bounds__(256) void k_count(const int* __restrict__ row, int* __restrict__ deg) {
  int e = blockIdx.x * blockDim.x + threadIdx.x;
  if (e < NE) atomicAdd(&deg[row[e]], 1);
}

__global__ __launch_bounds__(256) void k_dinv(const int* __restrict__ deg, float* __restrict__ dinv) {
  int i = blockIdx.x * blockDim.x + threadIdx.x;
  if (i < NN) {
    int d = deg[i];
    dinv[i] = (d > 0) ? rsqrtf((float)d) : 0.0f;
  }
}

// single-block exclusive scan of deg[0..NN) -> row_off  (known-correct; ~40us, optimize later)
__global__ __launch_bounds__(1024) void k_scan(const int* __restrict__ deg, int* __restrict__ row_off) {
  __shared__ int sm[1024];
  __shared__ int running;
  const int tid = threadIdx.x;
  if (tid == 0) running = 0;
  __syncthreads();
  for (int base = 0; base < NN; base += 1024) {
    int i = base + tid;
    int v = (i < NN) ? deg[i] : 0;
    sm[tid] = v;
    __syncthreads();
    for (int off = 1; off < 1024; off <<= 1) {
      int t = (tid >= off) ? sm[tid - off] : 0;
      __syncthreads();
      if (tid >= off) sm[tid] += t;
      __syncthreads();
    }
    int excl = sm[tid] - v;
    int run0 = running;
    if (i < NN) row_off[i] = run0 + excl;
    __syncthreads();
    if (tid == 0) running = run0 + sm[1023];
    __syncthreads();
  }
  if (tid == 0) row_off[NN] = NE;
}

__global__ __launch_bounds__(256) void k_fill(const int* __restrict__ row, const int* __restrict__ col,
    const int* __restrict__ row_off, int* __restrict__ cursor, const float* __restrict__ dinv,
    int* __restrict__ csr_col, float* __restrict__ csr_val) {
  int e = blockIdx.x * blockDim.x + threadIdx.x;
  if (e < NE) {
    int r = row[e], c = col[e];
    int pos = row_off[r] + atomicAdd(&cursor[r], 1);
    csr_col[pos] = c;
    csr_val[pos] = -dinv[r] * dinv[c];
  }
}

// ---------------- casts ----------------

// W[s][k][n] f32  ->  Bt[s][n][k] bf16  (transposed so GEMM B-fragments are k-contiguous)
__global__ __launch_bounds__(256) void k_wcast(const float* __restrict__ W, unsigned short* __restrict__ Bt) {
  int t = blockIdx.x * 256 + threadIdx.x;     // 8*512*64 threads
  int s = t >> 15;
  int r = t & 32767;
  int n = r >> 6;
  int k8 = (r & 63) * 8;
  const float* w = W + ((size_t)s << 18);
  ushort8v v;
  #pragma unroll
  for (int j = 0; j < 8; ++j) v[j] = f2bf(w[(size_t)(k8 + j) * CC + n]);
  *(ushort8v*)&Bt[((size_t)s << 18) + (size_t)n * CC + k8] = v;
}

// x f32 -> Abf bf16 (row-major [NN][CC])
__global__ __launch_bounds__(256) void k_xcast(const float* __restrict__ x, unsigned short* __restrict__ abf) {
  size_t i = ((size_t)blockIdx.x * 256 + threadIdx.x) * 8;
  if (i >= (size_t)NN * CC) return;
  const float4* p = (const float4*)&x[i];
  float4 a = p[0], b = p[1];
  ushort8v v;
  v[0] = f2bf(a.x); v[1] = f2bf(a.y); v[2] = f2bf(a.z); v[3] = f2bf(a.w);
  v[4] = f2bf(b.x); v[5] = f2bf(b.y); v[6] = f2bf(b.z); v[7] = f2bf(b.w);
  *(ushort8v*)&abf[i] = v;
}

// ---------------- SPMM: dst = alpha*L*src + beta*prev ; also writes bf16 copy ----------------

__global__ __launch_bounds__(128) void k_spmm(const float* __restrict__ src,
    const float* __restrict__ prev, float* __restrict__ dst, unsigned short* __restrict__ abf,
    const int* __restrict__ row_off, const int* __restrict__ csr_col,
    const float* __restrict__ csr_val, float alpha, float beta)
{
  const int i = blockIdx.x;
  const int c = threadIdx.x * 4;
  const int e0 = row_off[i];
  const int e1 = row_off[i + 1];
  float4 acc = make_float4(0.f, 0.f, 0.f, 0.f);
  for (int e = e0; e < e1; ++e) {
    int j = csr_col[e];
    float v = csr_val[e];
    const float4 xv = *(const float4*)&src[(size_t)j * CC + c];
    acc.x += v * xv.x; acc.y += v * xv.y; acc.z += v * xv.z; acc.w += v * xv.w;
  }
  float4 r;
  if (beta != 0.0f) {
    const float4 p = *(const float4*)&prev[(size_t)i * CC + c];
    r.x = alpha * acc.x + beta * p.x;
    r.y = alpha * acc.y + beta * p.y;
    r.z = alpha * acc.z + beta * p.z;
    r.w = alpha * acc.w + beta * p.w;
  } else {
    r.x = alpha * acc.x; r.y = alpha * acc.y; r.z = alpha * acc.z; r.w = alpha * acc.w;
  }
  *(float4*)&dst[(size_t)i * CC + c] = r;
  ushort4v bv;
  bv[0] = f2bf(r.x); bv[1] = f2bf(r.y); bv[2] = f2bf(r.z); bv[3] = f2bf(r.w);
  *(ushort4v*)&abf[(size_t)i * CC + c] = bv;
}

// ---------------- MFMA GEMM: C (+)= A[NP,512](bf16) @ Bt[512,512]^T (bf16), f32 out ----------------
// 128x128 tile, BK=32, 4 waves each owning 64x64 (4x4 fragments of 16x16x32).

__global__ __launch_bounds__(256) void k_gemm(const unsigned short* __restrict__ A,
    const unsigned short* __restrict__ Bt, float* __restrict__ C,
    const float* __restrict__ bias, int first)
{
  __shared__ unsigned short smA[128 * 32];
  __shared__ unsigned short smB[128 * 32];
  const int tid  = threadIdx.x;
  const int lane = tid & 63;
  const int wave = tid >> 6;
  const int wr = wave >> 1, wc = wave & 1;
  const int m0 = blockIdx.y * 128;
  const int n0 = blockIdx.x * 128;
  const int srow = lane >> 2;          // staging: row within 16-row chunk
  const int skc  = (lane & 3) * 8;     // staging: k offset

  f32x4 acc[4][4] = {};

  for (int k0 = 0; k0 < CC; k0 += 32) {
    #pragma unroll
    for (int i = 0; i < 2; ++i) {
      int row = wave * 32 + i * 16;
      gload_lds16(&A[(size_t)(m0 + row + srow) * CC + k0 + skc], &smA[row * 32]);
      gload_lds16(&Bt[(size_t)(n0 + row + srow) * CC + k0 + skc], &smB[row * 32]);
    }
    __syncthreads();

    short8 af[4], bfv[4];
    #pragma unroll
    for (int f = 0; f < 4; ++f) {
      af[f]  = *(const short8*)&smA[(wr * 64 + f * 16 + (lane & 15)) * 32 + (lane >> 4) * 8];
      bfv[f] = *(const short8*)&smB[(wc * 64 + f * 16 + (lane & 15)) * 32 + (lane >> 4) * 8];
    }
    #pragma unroll
    for (int fm = 0; fm < 4; ++fm)
      #pragma unroll
      for (int fn = 0; fn < 4; ++fn)
        acc[fm][fn] = __builtin_amdgcn_mfma_f32_16x16x32_bf16(af[fm], bfv[fn], acc[fm][fn], 0, 0, 0);
    __syncthreads();
  }

  const int prow = (lane >> 4) * 4;
  const int pcol = lane & 15;
  #pragma unroll
  for (int fm = 0; fm < 4; ++fm) {
    #pragma unroll
    for (int fn = 0; fn < 4; ++fn) {
      int gcol = n0 + wc * 64 + fn * 16 + pcol;
      #pragma unroll
      for (int j = 0; j < 4; ++j) {
        int grow = m0 + wr * 64 + fm * 16 + prow + j;
        if (grow < NN) {
          size_t off = (size_t)grow * CC + gcol;
          float v = acc[fm][fn][j];
          if (first) C[off] = v + bias[gcol];
          else       C[off] += v;
        }
      }
    }
  }
}

// ---------------- launch ----------------

extern "C" void kernel_launch(void* const* d_in, const int* in_sizes, int n_in,
                              void* d_out, int out_size, void* d_ws, size_t ws_size,
                              hipStream_t stream) {
  const float* x      = (const float*)d_in[0];
  const int*   row    = (const int*)d_in[1];
  const int*   col    = row + NE;
  const float* weight = (const float*)d_in[2];
  const float* bias   = (const float*)d_in[3];
  float* out = (float*)d_out;

  // workspace layout (~103 MB), 16B-aligned bf16 buffers first
  unsigned short* Abf = (unsigned short*)d_ws;                 // NP*CC bf16
  unsigned short* Bt  = Abf + (size_t)NP * CC;                 // 8*CC*CC bf16
  float* TxA     = (float*)(Bt + (size_t)KW * CC * CC);        // NN*CC f32
  float* TxB     = TxA + (size_t)NN * CC;
  float* dinv    = TxB + (size_t)NN * CC;
  float* csr_val = dinv + NN;
  int*   deg     = (int*)(csr_val + NE);
  int*   cursor  = deg + NN;
  int*   row_off = cursor + NN;
  int*   csr_col = row_off + NN + 1;

  k_zero<<<(NN + 255) / 256, 256, 0, stream>>>(deg, cursor);
  k_count<<<(NE + 255) / 256, 256, 0, stream>>>(row, deg);
  k_dinv<<<(NN + 255) / 256, 256, 0, stream>>>(deg, dinv);
  k_scan<<<1, 1024, 0, stream>>>(deg, row_off);
  k_fill<<<(NE + 255) / 256, 256, 0, stream>>>(row, col, row_off, cursor, dinv, csr_col, csr_val);

  k_wcast<<<(KW * CC * CC / 8 + 255) / 256, 256, 0, stream>>>(weight, Bt);
  k_xcast<<<((NN * CC / 8) + 255) / 256, 256, 0, stream>>>(x, Abf);

  dim3 gg(CC / 128, NP / 128);

  // out = x @ W0 + bias
  k_gemm<<<gg, 256, 0, stream>>>(Abf, Bt, out, bias, 1);

  // Tx1 = L x
  k_spmm<<<NN, 128, 0, stream>>>(x, x, TxA, Abf, row_off, csr_col, csr_val, 1.0f, 0.0f);
  k_gemm<<<gg, 256, 0, stream>>>(Abf, Bt + (size_t)1 * CC * CC, out, bias, 0);

  // Tx2 = 2 L Tx1 - x
  k_spmm<<<NN, 128, 0, stream>>>(TxA, x, TxB, Abf, row_off, csr_col, csr_val, 2.0f, -1.0f);
  k_gemm<<<gg, 256, 0, stream>>>(Abf, Bt + (size_t)2 * CC * CC, out, bias, 0);

  // k = 3..7: Tx_k = 2 L Tx_{k-1} - Tx_{k-2}, ping-pong in place
  float* bufs[2] = { TxA, TxB };
  for (int k = 3; k < KW; ++k) {
    float* dst = bufs[(k + 1) & 1];
    float* src = bufs[k & 1];
    k_spmm<<<NN, 128, 0, stream>>>(src, dst, dst, Abf, row_off, csr_col, csr_val, 2.0f, -1.0f);
    k_gemm<<<gg, 256, 0, stream>>>(Abf, Bt + (size_t)k * CC * CC, out, bias, 0);
  }
}

// Round 3
// 608.563 us; speedup vs baseline: 2.7767x; 1.2985x over previous
//
#include <hip/hip_runtime.h>

#define NN 20000
#define NP 20096   // M padded to multiple of 128
#define NE 150000
#define CC 512
#define KW 8
#define KT 4096    // KW*CC — fused GEMM K

typedef __attribute__((ext_vector_type(8))) short short8;
typedef __attribute__((ext_vector_type(4))) float f32x4;
typedef __attribute__((ext_vector_type(4))) unsigned short ushort4v;
typedef __attribute__((ext_vector_type(8))) unsigned short ushort8v;

__device__ inline unsigned short f2bf(float f) {   // RNE f32->bf16
  unsigned u = __builtin_bit_cast(unsigned, f);
  u += 0x7fffu + ((u >> 16) & 1u);
  return (unsigned short)(u >> 16);
}

__device__ inline void gload_lds16(const void* g, void* l) {
  __builtin_amdgcn_global_load_lds(
      (const __attribute__((address_space(1))) unsigned int*)g,
      (__attribute__((address_space(3))) unsigned int*)l, 16, 0, 0);
}

// ---------------- setup kernels ----------------

__global__ __launch_bounds__(256) void k_zero(int* __restrict__ deg, int* __restrict__ cursor) {
  int i = blockIdx.x * blockDim.x + threadIdx.x;
  if (i < NN) { deg[i] = 0; cursor[i] = 0; }
}

__global__ __launch_bounds__(256) void k_count(const int* __restrict__ row, int* __restrict__ deg) {
  int e = blockIdx.x * blockDim.x + threadIdx.x;
  if (e < NE) atomicAdd(&deg[row[e]], 1);
}

__global__ __launch_bounds__(256) void k_dinv(const int* __restrict__ deg, float* __restrict__ dinv) {
  int i = blockIdx.x * blockDim.x + threadIdx.x;
  if (i < NN) {
    int d = deg[i];
    dinv[i] = (d > 0) ? rsqrtf((float)d) : 0.0f;
  }
}

__global__ __launch_bounds__(1024) void k_scan(const int* __restrict__ deg, int* __restrict__ row_off) {
  __shared__ int sm[1024];
  __shared__ int running;
  const int tid = threadIdx.x;
  if (tid == 0) running = 0;
  __syncthreads();
  for (int base = 0; base < NN; base += 1024) {
    int i = base + tid;
    int v = (i < NN) ? deg[i] : 0;
    sm[tid] = v;
    __syncthreads();
    for (int off = 1; off < 1024; off <<= 1) {
      int t = (tid >= off) ? sm[tid - off] : 0;
      __syncthreads();
      if (tid >= off) sm[tid] += t;
      __syncthreads();
    }
    int excl = sm[tid] - v;
    int run0 = running;
    if (i < NN) row_off[i] = run0 + excl;
    __syncthreads();
    if (tid == 0) running = run0 + sm[1023];
    __syncthreads();
  }
  if (tid == 0) row_off[NN] = NE;
}

__global__ __launch_bounds__(256) void k_fill(const int* __restrict__ row, const int* __restrict__ col,
    const int* __restrict__ row_off, int* __restrict__ cursor, const float* __restrict__ dinv,
    int* __restrict__ csr_col, float* __restrict__ csr_val) {
  int e = blockIdx.x * blockDim.x + threadIdx.x;
  if (e < NE) {
    int r = row[e], c = col[e];
    int pos = row_off[r] + atomicAdd(&cursor[r], 1);
    csr_col[pos] = c;
    csr_val[pos] = -dinv[r] * dinv[c];
  }
}

// ---------------- casts ----------------

// W[s][k][n] f32 -> Bt[n][s*512+k] bf16, via LDS 64x64 transpose tiles (coalesced both sides)
__global__ __launch_bounds__(256) void k_wcast(const float* __restrict__ W, unsigned short* __restrict__ Bt) {
  __shared__ float sm[64][68];
  const int t = blockIdx.x;            // 0..511 : 8 slices * 64 tiles
  const int s = t >> 6;
  const int rem = t & 63;
  const int kt0 = (rem >> 3) * 64;
  const int nt0 = (rem & 7) * 64;
  const float* w = W + ((size_t)s << 18);
  const int tid = threadIdx.x;
  #pragma unroll
  for (int i = 0; i < 4; ++i) {
    int f = tid + i * 256;             // 1024 float4s = 64x64 f32
    int r = f >> 4;
    int c4 = f & 15;
    float4 v = *(const float4*)&w[(size_t)(kt0 + r) * CC + nt0 + c4 * 4];
    sm[r][c4 * 4 + 0] = v.x; sm[r][c4 * 4 + 1] = v.y;
    sm[r][c4 * 4 + 2] = v.z; sm[r][c4 * 4 + 3] = v.w;
  }
  __syncthreads();
  #pragma unroll
  for (int i = 0; i < 2; ++i) {
    int g = tid + i * 256;             // 512 ushort8s
    int nl = g >> 3;
    int k8 = (g & 7) * 8;
    ushort8v o;
    #pragma unroll
    for (int j = 0; j < 8; ++j) o[j] = f2bf(sm[k8 + j][nl]);
    *(ushort8v*)&Bt[(size_t)(nt0 + nl) * KT + s * CC + kt0 + k8] = o;
  }
}

// x f32 -> TxAll slice 0 (row stride KT)
__global__ __launch_bounds__(256) void k_xcast(const float* __restrict__ x, unsigned short* __restrict__ txall) {
  size_t t = (size_t)blockIdx.x * 256 + threadIdx.x;
  size_t idx = t * 8;
  if (idx >= (size_t)NN * CC) return;
  size_t r = idx >> 9;
  int c = (int)(idx & 511);
  const float4* p = (const float4*)&x[idx];
  float4 a = p[0], b = p[1];
  ushort8v v;
  v[0] = f2bf(a.x); v[1] = f2bf(a.y); v[2] = f2bf(a.z); v[3] = f2bf(a.w);
  v[4] = f2bf(b.x); v[5] = f2bf(b.y); v[6] = f2bf(b.z); v[7] = f2bf(b.w);
  *(ushort8v*)&txall[r * KT + c] = v;
}

// ---------------- SPMM: dst = alpha*L*src + beta*prev ; writes bf16 slice into TxAll ----------------
// one block per node, 128 threads * 4 ch; edge loop unrolled x4 for memory parallelism

__global__ __launch_bounds__(128) void k_spmm(const float* __restrict__ src,
    const float* __restrict__ prev, float* __restrict__ dst, unsigned short* __restrict__ abf,
    const int* __restrict__ row_off, const int* __restrict__ csr_col,
    const float* __restrict__ csr_val, float alpha, float beta, int wf32)
{
  const int i = blockIdx.x;
  const int c = threadIdx.x * 4;
  const int e0 = row_off[i];
  const int e1 = row_off[i + 1];
  float4 a0 = make_float4(0.f,0.f,0.f,0.f), a1 = a0, a2 = a0, a3 = a0;
  int e = e0;
  for (; e + 4 <= e1; e += 4) {
    int j0 = csr_col[e], j1 = csr_col[e+1], j2 = csr_col[e+2], j3 = csr_col[e+3];
    float v0 = csr_val[e], v1 = csr_val[e+1], v2 = csr_val[e+2], v3 = csr_val[e+3];
    const float4 x0 = *(const float4*)&src[(size_t)j0 * CC + c];
    const float4 x1 = *(const float4*)&src[(size_t)j1 * CC + c];
    const float4 x2 = *(const float4*)&src[(size_t)j2 * CC + c];
    const float4 x3 = *(const float4*)&src[(size_t)j3 * CC + c];
    a0.x += v0*x0.x; a0.y += v0*x0.y; a0.z += v0*x0.z; a0.w += v0*x0.w;
    a1.x += v1*x1.x; a1.y += v1*x1.y; a1.z += v1*x1.z; a1.w += v1*x1.w;
    a2.x += v2*x2.x; a2.y += v2*x2.y; a2.z += v2*x2.z; a2.w += v2*x2.w;
    a3.x += v3*x3.x; a3.y += v3*x3.y; a3.z += v3*x3.z; a3.w += v3*x3.w;
  }
  for (; e < e1; ++e) {
    int j = csr_col[e];
    float v = csr_val[e];
    const float4 xv = *(const float4*)&src[(size_t)j * CC + c];
    a0.x += v*xv.x; a0.y += v*xv.y; a0.z += v*xv.z; a0.w += v*xv.w;
  }
  float4 s;
  s.x = (a0.x + a1.x) + (a2.x + a3.x);
  s.y = (a0.y + a1.y) + (a2.y + a3.y);
  s.z = (a0.z + a1.z) + (a2.z + a3.z);
  s.w = (a0.w + a1.w) + (a2.w + a3.w);
  float4 r;
  if (beta != 0.0f) {
    const float4 p = *(const float4*)&prev[(size_t)i * CC + c];
    r.x = alpha * s.x + beta * p.x;
    r.y = alpha * s.y + beta * p.y;
    r.z = alpha * s.z + beta * p.z;
    r.w = alpha * s.w + beta * p.w;
  } else {
    r.x = alpha * s.x; r.y = alpha * s.y; r.z = alpha * s.z; r.w = alpha * s.w;
  }
  if (wf32) *(float4*)&dst[(size_t)i * CC + c] = r;
  ushort4v bv;
  bv[0] = f2bf(r.x); bv[1] = f2bf(r.y); bv[2] = f2bf(r.z); bv[3] = f2bf(r.w);
  *(ushort4v*)&abf[(size_t)i * KT + c] = bv;
}

// ---------------- fused MFMA GEMM: C = TxAll[NP,4096] @ Bt[512,4096]^T + bias ----------------
// 128x128 tile, BK=32, 4 waves x (4x4) 16x16x32 fragments; single C write (no RMW).

__global__ __launch_bounds__(256) void k_gemm(const unsigned short* __restrict__ A,
    const unsigned short* __restrict__ Bt, float* __restrict__ C,
    const float* __restrict__ bias)
{
  __shared__ unsigned short smA[128 * 32];
  __shared__ unsigned short smB[128 * 32];
  const int tid  = threadIdx.x;
  const int lane = tid & 63;
  const int wave = tid >> 6;
  const int wr = wave >> 1, wc = wave & 1;

  // bijective XCD swizzle: the 4 n-blocks sharing an A-panel land on one XCD
  const int nwg = (NP / 128) * 4;            // 628
  int bid = blockIdx.x;
  int q = nwg >> 3, rr = nwg & 7;
  int xcd = bid & 7, lid = bid >> 3;
  int wgid = (xcd < rr ? xcd * (q + 1) : rr * (q + 1) + (xcd - rr) * q) + lid;
  const int m0 = (wgid >> 2) * 128;
  const int n0 = (wgid & 3) * 128;

  const int srow = lane >> 2;
  const int skc  = (lane & 3) * 8;

  f32x4 acc[4][4] = {};

  for (int k0 = 0; k0 < KT; k0 += 32) {
    #pragma unroll
    for (int i = 0; i < 2; ++i) {
      int row = wave * 32 + i * 16;
      gload_lds16(&A[(size_t)(m0 + row + srow) * KT + k0 + skc], &smA[row * 32]);
      gload_lds16(&Bt[(size_t)(n0 + row + srow) * KT + k0 + skc], &smB[row * 32]);
    }
    __syncthreads();

    short8 af[4], bfv[4];
    #pragma unroll
    for (int f = 0; f < 4; ++f) {
      af[f]  = *(const short8*)&smA[(wr * 64 + f * 16 + (lane & 15)) * 32 + (lane >> 4) * 8];
      bfv[f] = *(const short8*)&smB[(wc * 64 + f * 16 + (lane & 15)) * 32 + (lane >> 4) * 8];
    }
    #pragma unroll
    for (int fm = 0; fm < 4; ++fm)
      #pragma unroll
      for (int fn = 0; fn < 4; ++fn)
        acc[fm][fn] = __builtin_amdgcn_mfma_f32_16x16x32_bf16(af[fm], bfv[fn], acc[fm][fn], 0, 0, 0);
    __syncthreads();
  }

  const int prow = (lane >> 4) * 4;
  const int pcol = lane & 15;
  #pragma unroll
  for (int fm = 0; fm < 4; ++fm) {
    #pragma unroll
    for (int fn = 0; fn < 4; ++fn) {
      int gcol = n0 + wc * 64 + fn * 16 + pcol;
      float bb = bias[gcol];
      #pragma unroll
      for (int j = 0; j < 4; ++j) {
        int grow = m0 + wr * 64 + fm * 16 + prow + j;
        if (grow < NN) C[(size_t)grow * CC + gcol] = acc[fm][fn][j] + bb;
      }
    }
  }
}

// ---------------- launch ----------------

extern "C" void kernel_launch(void* const* d_in, const int* in_sizes, int n_in,
                              void* d_out, int out_size, void* d_ws, size_t ws_size,
                              hipStream_t stream) {
  const float* x      = (const float*)d_in[0];
  const int*   row    = (const int*)d_in[1];
  const int*   col    = row + NE;
  const float* weight = (const float*)d_in[2];
  const float* bias   = (const float*)d_in[3];
  float* out = (float*)d_out;

  // workspace (~211 MB); d_out doubles as the second f32 recurrence buffer
  unsigned short* TxAll = (unsigned short*)d_ws;               // NP*KT bf16
  unsigned short* Bt    = TxAll + (size_t)NP * KT;             // 512*KT bf16
  float* TxA     = (float*)(Bt + (size_t)CC * KT);             // NN*CC f32
  float* dinv    = TxA + (size_t)NN * CC;
  float* csr_val = dinv + NN;
  int*   deg     = (int*)(csr_val + NE);
  int*   cursor  = deg + NN;
  int*   row_off = cursor + NN;
  int*   csr_col = row_off + NN + 1;
  float* TxB     = out;                                        // reused as scratch; GEMM overwrites

  k_zero<<<(NN + 255) / 256, 256, 0, stream>>>(deg, cursor);
  k_count<<<(NE + 255) / 256, 256, 0, stream>>>(row, deg);
  k_dinv<<<(NN + 255) / 256, 256, 0, stream>>>(deg, dinv);
  k_scan<<<1, 1024, 0, stream>>>(deg, row_off);
  k_fill<<<(NE + 255) / 256, 256, 0, stream>>>(row, col, row_off, cursor, dinv, csr_col, csr_val);

  k_wcast<<<512, 256, 0, stream>>>(weight, Bt);
  k_xcast<<<(NN * CC / 8 + 255) / 256, 256, 0, stream>>>(x, TxAll);

  // Tx1 = L x          -> TxA, slice 1
  k_spmm<<<NN, 128, 0, stream>>>(x, x, TxA, TxAll + 1 * CC, row_off, csr_col, csr_val, 1.0f, 0.0f, 1);
  // Tx2 = 2 L Tx1 - x  -> TxB(out), slice 2
  k_spmm<<<NN, 128, 0, stream>>>(TxA, x, TxB, TxAll + 2 * CC, row_off, csr_col, csr_val, 2.0f, -1.0f, 1);
  // k = 3..7 ping-pong; last pass skips the dead f32 store
  float* bufs[2] = { TxA, TxB };
  for (int k = 3; k < KW; ++k) {
    float* dst = bufs[(k + 1) & 1];
    float* src = bufs[k & 1];
    k_spmm<<<NN, 128, 0, stream>>>(src, dst, dst, TxAll + (size_t)k * CC, row_off, csr_col, csr_val,
                                   2.0f, -1.0f, (k < KW - 1) ? 1 : 0);
  }

  // single fused GEMM: out = [Tx_0 | ... | Tx_7] @ [W_0; ...; W_7] + bias
  k_gemm<<<(NP / 128) * 4, 256, 0, stream>>>(TxAll, Bt, out, bias);
}

// Round 4
// 604.260 us; speedup vs baseline: 2.7964x; 1.0071x over previous
//
#include <hip/hip_runtime.h>

#define NN 20000
#define NP 20096   // M padded to multiple of 128
#define NE 150000
#define CC 512
#define KW 8
#define KT 4096    // KW*CC — fused GEMM K
#define SCB 20     // scan blocks: ceil(NN/1024)

typedef __attribute__((ext_vector_type(8))) short short8;
typedef __attribute__((ext_vector_type(4))) float f32x4;
typedef __attribute__((ext_vector_type(4))) unsigned short ushort4v;
typedef __attribute__((ext_vector_type(8))) unsigned short ushort8v;

__device__ inline unsigned short f2bf(float f) {   // RNE f32->bf16
  unsigned u = __builtin_bit_cast(unsigned, f);
  u += 0x7fffu + ((u >> 16) & 1u);
  return (unsigned short)(u >> 16);
}

__device__ inline void gload_lds16(const void* g, void* l) {
  __builtin_amdgcn_global_load_lds(
      (const __attribute__((address_space(1))) unsigned int*)g,
      (__attribute__((address_space(3))) unsigned int*)l, 16, 0, 0);
}

// ---------------- setup kernels ----------------

__global__ __launch_bounds__(256) void k_zero(int* __restrict__ deg, int* __restrict__ cursor) {
  int i = blockIdx.x * blockDim.x + threadIdx.x;
  if (i < NN) { deg[i] = 0; cursor[i] = 0; }
}

__global__ __launch_bounds__(256) void k_count(const int* __restrict__ row, int* __restrict__ deg) {
  int e = blockIdx.x * blockDim.x + threadIdx.x;
  if (e < NE) atomicAdd(&deg[row[e]], 1);
}

__global__ __launch_bounds__(256) void k_dinv(const int* __restrict__ deg, float* __restrict__ dinv) {
  int i = blockIdx.x * blockDim.x + threadIdx.x;
  if (i < NN) {
    int d = deg[i];
    dinv[i] = (d > 0) ? rsqrtf((float)d) : 0.0f;
  }
}

// hierarchical scan: A) per-block 1024 scan, B) scan of 20 block sums, C) add offsets
__global__ __launch_bounds__(1024) void k_scanA(const int* __restrict__ deg,
    int* __restrict__ row_off, int* __restrict__ bsum) {
  __shared__ int sm[1024];
  const int b = blockIdx.x, tid = threadIdx.x;
  int i = b * 1024 + tid;
  int v = (i < NN) ? deg[i] : 0;
  sm[tid] = v;
  __syncthreads();
  #pragma unroll
  for (int off = 1; off < 1024; off <<= 1) {
    int t = (tid >= off) ? sm[tid - off] : 0;
    __syncthreads();
    if (tid >= off) sm[tid] += t;
    __syncthreads();
  }
  if (i < NN) row_off[i] = sm[tid] - v;
  if (tid == 1023) bsum[b] = sm[1023];
}

__global__ __launch_bounds__(64) void k_scanB(int* __restrict__ bsum) {
  if (threadIdx.x == 0) {
    int run = 0;
    for (int b = 0; b < SCB; ++b) { int t = bsum[b]; bsum[b] = run; run += t; }
  }
}

__global__ __launch_bounds__(1024) void k_scanC(int* __restrict__ row_off, const int* __restrict__ bsum) {
  int i = blockIdx.x * 1024 + threadIdx.x;
  if (i < NN) row_off[i] += bsum[blockIdx.x];
  if (i == NN - 1) row_off[NN] = NE;
}

__global__ __launch_bounds__(256) void k_fill(const int* __restrict__ row, const int* __restrict__ col,
    const int* __restrict__ row_off, int* __restrict__ cursor, const float* __restrict__ dinv,
    int* __restrict__ csr_col, float* __restrict__ csr_val) {
  int e = blockIdx.x * blockDim.x + threadIdx.x;
  if (e < NE) {
    int r = row[e], c = col[e];
    int pos = row_off[r] + atomicAdd(&cursor[r], 1);
    csr_col[pos] = c;
    csr_val[pos] = -dinv[r] * dinv[c];
  }
}

// ---------------- casts ----------------

// W[s][k][n] f32 -> Bt[n][s*512+k] bf16, via LDS 64x64 transpose tiles
__global__ __launch_bounds__(256) void k_wcast(const float* __restrict__ W, unsigned short* __restrict__ Bt) {
  __shared__ float sm[64][68];
  const int t = blockIdx.x;            // 0..511 : 8 slices * 64 tiles
  const int s = t >> 6;
  const int rem = t & 63;
  const int kt0 = (rem >> 3) * 64;
  const int nt0 = (rem & 7) * 64;
  const float* w = W + ((size_t)s << 18);
  const int tid = threadIdx.x;
  #pragma unroll
  for (int i = 0; i < 4; ++i) {
    int f = tid + i * 256;
    int r = f >> 4;
    int c4 = f & 15;
    float4 v = *(const float4*)&w[(size_t)(kt0 + r) * CC + nt0 + c4 * 4];
    sm[r][c4 * 4 + 0] = v.x; sm[r][c4 * 4 + 1] = v.y;
    sm[r][c4 * 4 + 2] = v.z; sm[r][c4 * 4 + 3] = v.w;
  }
  __syncthreads();
  #pragma unroll
  for (int i = 0; i < 2; ++i) {
    int g = tid + i * 256;
    int nl = g >> 3;
    int k8 = (g & 7) * 8;
    ushort8v o;
    #pragma unroll
    for (int j = 0; j < 8; ++j) o[j] = f2bf(sm[k8 + j][nl]);
    *(ushort8v*)&Bt[(size_t)(nt0 + nl) * KT + s * CC + kt0 + k8] = o;
  }
}

// x f32 -> TxAll slice 0 (row stride KT)
__global__ __launch_bounds__(256) void k_xcast(const float* __restrict__ x, unsigned short* __restrict__ txall) {
  size_t t = (size_t)blockIdx.x * 256 + threadIdx.x;
  size_t idx = t * 8;
  if (idx >= (size_t)NN * CC) return;
  size_t r = idx >> 9;
  int c = (int)(idx & 511);
  const float4* p = (const float4*)&x[idx];
  float4 a = p[0], b = p[1];
  ushort8v v;
  v[0] = f2bf(a.x); v[1] = f2bf(a.y); v[2] = f2bf(a.z); v[3] = f2bf(a.w);
  v[4] = f2bf(b.x); v[5] = f2bf(b.y); v[6] = f2bf(b.z); v[7] = f2bf(b.w);
  *(ushort8v*)&txall[r * KT + c] = v;
}

// ---------------- SPMM: dst = alpha*L*src + beta*prev ; writes bf16 slice into TxAll ----
// one block per node, 256 threads: 2-way edge split (es) x 128 channel-threads,
// each sub-lane unrolls x4 -> up to 8 gathers in flight per row.

__global__ __launch_bounds__(256) void k_spmm(const float* __restrict__ src,
    const float* __restrict__ prev, float* __restrict__ dst, unsigned short* __restrict__ abf,
    const int* __restrict__ row_off, const int* __restrict__ csr_col,
    const float* __restrict__ csr_val, float alpha, float beta, int wf32)
{
  __shared__ float4 smx[128];
  const int i = blockIdx.x;
  const int tid = threadIdx.x;
  const int es = tid >> 7;          // 0/1 : edge parity
  const int c = (tid & 127) * 4;    // channel offset
  const int e0 = row_off[i];
  const int e1 = row_off[i + 1];
  float4 a0 = make_float4(0.f,0.f,0.f,0.f), a1 = a0, a2 = a0, a3 = a0;
  int e = e0 + es;
  for (; e + 6 < e1; e += 8) {
    int j0 = csr_col[e], j1 = csr_col[e+2], j2 = csr_col[e+4], j3 = csr_col[e+6];
    float v0 = csr_val[e], v1 = csr_val[e+2], v2 = csr_val[e+4], v3 = csr_val[e+6];
    const float4 x0 = *(const float4*)&src[(size_t)j0 * CC + c];
    const float4 x1 = *(const float4*)&src[(size_t)j1 * CC + c];
    const float4 x2 = *(const float4*)&src[(size_t)j2 * CC + c];
    const float4 x3 = *(const float4*)&src[(size_t)j3 * CC + c];
    a0.x += v0*x0.x; a0.y += v0*x0.y; a0.z += v0*x0.z; a0.w += v0*x0.w;
    a1.x += v1*x1.x; a1.y += v1*x1.y; a1.z += v1*x1.z; a1.w += v1*x1.w;
    a2.x += v2*x2.x; a2.y += v2*x2.y; a2.z += v2*x2.z; a2.w += v2*x2.w;
    a3.x += v3*x3.x; a3.y += v3*x3.y; a3.z += v3*x3.z; a3.w += v3*x3.w;
  }
  for (; e < e1; e += 2) {
    int j = csr_col[e];
    float v = csr_val[e];
    const float4 xv = *(const float4*)&src[(size_t)j * CC + c];
    a0.x += v*xv.x; a0.y += v*xv.y; a0.z += v*xv.z; a0.w += v*xv.w;
  }
  float4 s;
  s.x = (a0.x + a1.x) + (a2.x + a3.x);
  s.y = (a0.y + a1.y) + (a2.y + a3.y);
  s.z = (a0.z + a1.z) + (a2.z + a3.z);
  s.w = (a0.w + a1.w) + (a2.w + a3.w);
  if (es == 1) smx[tid & 127] = s;
  __syncthreads();
  if (es == 0) {
    const float4 o = smx[tid];
    s.x += o.x; s.y += o.y; s.z += o.z; s.w += o.w;
    float4 r;
    if (beta != 0.0f) {
      const float4 p = *(const float4*)&prev[(size_t)i * CC + c];
      r.x = alpha * s.x + beta * p.x;
      r.y = alpha * s.y + beta * p.y;
      r.z = alpha * s.z + beta * p.z;
      r.w = alpha * s.w + beta * p.w;
    } else {
      r.x = alpha * s.x; r.y = alpha * s.y; r.z = alpha * s.z; r.w = alpha * s.w;
    }
    if (wf32) *(float4*)&dst[(size_t)i * CC + c] = r;
    ushort4v bv;
    bv[0] = f2bf(r.x); bv[1] = f2bf(r.y); bv[2] = f2bf(r.z); bv[3] = f2bf(r.w);
    *(ushort4v*)&abf[(size_t)i * KT + c] = bv;
  }
}

// ---------------- split-K MFMA GEMM: P{0,1} = TxAll[NP,4096] @ Bt[512,4096]^T halves ----
// one dispatch, 1256 blocks (8x157 -> perfect bijective XCD swizzle), 128x128 tile, BK=32.

__global__ __launch_bounds__(256) void k_gemm(const unsigned short* __restrict__ A,
    const unsigned short* __restrict__ Bt, float* __restrict__ P0, float* __restrict__ P1)
{
  __shared__ unsigned short smA[128 * 32];
  __shared__ unsigned short smB[128 * 32];
  const int tid  = threadIdx.x;
  const int lane = tid & 63;
  const int wave = tid >> 6;
  const int wr = wave >> 1, wc = wave & 1;

  // 1256 = 8 * 157 : wgid = xcd*157 + lid is bijective
  int bid = blockIdx.x;
  int wgid = (bid & 7) * 157 + (bid >> 3);
  int h = (wgid >= 628) ? 1 : 0;
  int rem = wgid - h * 628;
  const int m0 = (rem >> 2) * 128;
  const int n0 = (rem & 3) * 128;
  float* __restrict__ P = h ? P1 : P0;
  const int kbeg = h * 2048;

  const int srow = lane >> 2;
  const int skc  = (lane & 3) * 8;

  f32x4 acc[4][4] = {};

  for (int k0 = kbeg; k0 < kbeg + 2048; k0 += 32) {
    #pragma unroll
    for (int i = 0; i < 2; ++i) {
      int row = wave * 32 + i * 16;
      gload_lds16(&A[(size_t)(m0 + row + srow) * KT + k0 + skc], &smA[row * 32]);
      gload_lds16(&Bt[(size_t)(n0 + row + srow) * KT + k0 + skc], &smB[row * 32]);
    }
    __syncthreads();

    short8 af[4], bfv[4];
    #pragma unroll
    for (int f = 0; f < 4; ++f) {
      af[f]  = *(const short8*)&smA[(wr * 64 + f * 16 + (lane & 15)) * 32 + (lane >> 4) * 8];
      bfv[f] = *(const short8*)&smB[(wc * 64 + f * 16 + (lane & 15)) * 32 + (lane >> 4) * 8];
    }
    #pragma unroll
    for (int fm = 0; fm < 4; ++fm)
      #pragma unroll
      for (int fn = 0; fn < 4; ++fn)
        acc[fm][fn] = __builtin_amdgcn_mfma_f32_16x16x32_bf16(af[fm], bfv[fn], acc[fm][fn], 0, 0, 0);
    __syncthreads();
  }

  const int prow = (lane >> 4) * 4;
  const int pcol = lane & 15;
  #pragma unroll
  for (int fm = 0; fm < 4; ++fm) {
    #pragma unroll
    for (int fn = 0; fn < 4; ++fn) {
      int gcol = n0 + wc * 64 + fn * 16 + pcol;
      #pragma unroll
      for (int j = 0; j < 4; ++j) {
        int grow = m0 + wr * 64 + fm * 16 + prow + j;
        if (grow < NN) P[(size_t)grow * CC + gcol] = acc[fm][fn][j];
      }
    }
  }
}

// out = P1(in place) + P0 + bias
__global__ __launch_bounds__(256) void k_add(float* __restrict__ out, const float* __restrict__ P0,
                                             const float* __restrict__ bias) {
  const size_t total = (size_t)NN * CC / 4;
  for (size_t t = (size_t)blockIdx.x * 256 + threadIdx.x; t < total; t += (size_t)gridDim.x * 256) {
    size_t idx = t * 4;
    int colq = (int)(idx & 511);
    float4 a = *(const float4*)&P0[idx];
    float4 b = *(float4*)&out[idx];
    const float4 bb = *(const float4*)&bias[colq];
    b.x += a.x + bb.x; b.y += a.y + bb.y; b.z += a.z + bb.z; b.w += a.w + bb.w;
    *(float4*)&out[idx] = b;
  }
}

// ---------------- launch ----------------

extern "C" void kernel_launch(void* const* d_in, const int* in_sizes, int n_in,
                              void* d_out, int out_size, void* d_ws, size_t ws_size,
                              hipStream_t stream) {
  const float* x      = (const float*)d_in[0];
  const int*   row    = (const int*)d_in[1];
  const int*   col    = row + NE;
  const float* weight = (const float*)d_in[2];
  const float* bias   = (const float*)d_in[3];
  float* out = (float*)d_out;

  // workspace (~211 MB); d_out doubles as recurrence buffer TxB and GEMM partial P1
  unsigned short* TxAll = (unsigned short*)d_ws;               // NP*KT bf16
  unsigned short* Bt    = TxAll + (size_t)NP * KT;             // 512*KT bf16
  float* TxA     = (float*)(Bt + (size_t)CC * KT);             // NN*CC f32 (also GEMM P0)
  float* dinv    = TxA + (size_t)NN * CC;
  float* csr_val = dinv + NN;
  int*   deg     = (int*)(csr_val + NE);
  int*   cursor  = deg + NN;
  int*   row_off = cursor + NN;
  int*   csr_col = row_off + NN + 1;
  int*   bsum    = csr_col + NE;
  float* TxB     = out;

  k_zero<<<(NN + 255) / 256, 256, 0, stream>>>(deg, cursor);
  k_count<<<(NE + 255) / 256, 256, 0, stream>>>(row, deg);
  k_dinv<<<(NN + 255) / 256, 256, 0, stream>>>(deg, dinv);
  k_scanA<<<SCB, 1024, 0, stream>>>(deg, row_off, bsum);
  k_scanB<<<1, 64, 0, stream>>>(bsum);
  k_scanC<<<SCB, 1024, 0, stream>>>(row_off, bsum);
  k_fill<<<(NE + 255) / 256, 256, 0, stream>>>(row, col, row_off, cursor, dinv, csr_col, csr_val);

  k_wcast<<<512, 256, 0, stream>>>(weight, Bt);
  k_xcast<<<(NN * CC / 8 + 255) / 256, 256, 0, stream>>>(x, TxAll);

  // Tx1 = L x          -> TxA, slice 1
  k_spmm<<<NN, 256, 0, stream>>>(x, x, TxA, TxAll + 1 * CC, row_off, csr_col, csr_val, 1.0f, 0.0f, 1);
  // Tx2 = 2 L Tx1 - x  -> TxB(out), slice 2
  k_spmm<<<NN, 256, 0, stream>>>(TxA, x, TxB, TxAll + 2 * CC, row_off, csr_col, csr_val, 2.0f, -1.0f, 1);
  // k = 3..7 ping-pong; last pass skips the dead f32 store
  float* bufs[2] = { TxA, TxB };
  for (int k = 3; k < KW; ++k) {
    float* dst = bufs[(k + 1) & 1];
    float* src = bufs[k & 1];
    k_spmm<<<NN, 256, 0, stream>>>(src, dst, dst, TxAll + (size_t)k * CC, row_off, csr_col, csr_val,
                                   2.0f, -1.0f, (k < KW - 1) ? 1 : 0);
  }

  // split-K fused GEMM (P0 = TxA region, P1 = out region), then combine + bias
  k_gemm<<<1256, 256, 0, stream>>>(TxAll, Bt, TxA, out);
  k_add<<<2048, 256, 0, stream>>>(out, TxA, bias);
}

// Round 5
// 559.360 us; speedup vs baseline: 3.0209x; 1.0803x over previous
//
#include <hip/hip_runtime.h>

#define NN 20000
#define NP 20096   // M padded to multiple of 128
#define NE 150000
#define CC 512
#define KW 8
#define KT 4096    // KW*CC — fused GEMM K
#define SCB 20     // scan blocks: ceil(NN/1024)

typedef __attribute__((ext_vector_type(8))) short short8;
typedef __attribute__((ext_vector_type(4))) float f32x4;
typedef __attribute__((ext_vector_type(4))) unsigned short ushort4v;
typedef __attribute__((ext_vector_type(8))) unsigned short ushort8v;

__device__ inline unsigned short f2bf(float f) {   // RNE f32->bf16
  unsigned u = __builtin_bit_cast(unsigned, f);
  u += 0x7fffu + ((u >> 16) & 1u);
  return (unsigned short)(u >> 16);
}

__device__ inline void gload_lds16(const void* g, void* l) {
  __builtin_amdgcn_global_load_lds(
      (const __attribute__((address_space(1))) unsigned int*)g,
      (__attribute__((address_space(3))) unsigned int*)l, 16, 0, 0);
}

// ---------------- setup kernels ----------------

__global__ __launch_bounds__(256) void k_zero(int* __restrict__ deg, int* __restrict__ cursor) {
  int i = blockIdx.x * blockDim.x + threadIdx.x;
  if (i < NN) { deg[i] = 0; cursor[i] = 0; }
}

__global__ __launch_bounds__(256) void k_count(const int* __restrict__ row, int* __restrict__ deg) {
  int e = blockIdx.x * blockDim.x + threadIdx.x;
  if (e < NE) atomicAdd(&deg[row[e]], 1);
}

__global__ __launch_bounds__(256) void k_dinv(const int* __restrict__ deg, float* __restrict__ dinv) {
  int i = blockIdx.x * blockDim.x + threadIdx.x;
  if (i < NN) {
    int d = deg[i];
    dinv[i] = (d > 0) ? rsqrtf((float)d) : 0.0f;
  }
}

// hierarchical scan: A) per-block 1024 scan, B) scan of 20 block sums, C) add offsets
__global__ __launch_bounds__(1024) void k_scanA(const int* __restrict__ deg,
    int* __restrict__ row_off, int* __restrict__ bsum) {
  __shared__ int sm[1024];
  const int b = blockIdx.x, tid = threadIdx.x;
  int i = b * 1024 + tid;
  int v = (i < NN) ? deg[i] : 0;
  sm[tid] = v;
  __syncthreads();
  #pragma unroll
  for (int off = 1; off < 1024; off <<= 1) {
    int t = (tid >= off) ? sm[tid - off] : 0;
    __syncthreads();
    if (tid >= off) sm[tid] += t;
    __syncthreads();
  }
  if (i < NN) row_off[i] = sm[tid] - v;
  if (tid == 1023) bsum[b] = sm[1023];
}

__global__ __launch_bounds__(64) void k_scanB(int* __restrict__ bsum) {
  if (threadIdx.x == 0) {
    int run = 0;
    for (int b = 0; b < SCB; ++b) { int t = bsum[b]; bsum[b] = run; run += t; }
  }
}

__global__ __launch_bounds__(1024) void k_scanC(int* __restrict__ row_off, const int* __restrict__ bsum) {
  int i = blockIdx.x * 1024 + threadIdx.x;
  if (i < NN) row_off[i] += bsum[blockIdx.x];
  if (i == NN - 1) row_off[NN] = NE;
}

__global__ __launch_bounds__(256) void k_fill(const int* __restrict__ row, const int* __restrict__ col,
    const int* __restrict__ row_off, int* __restrict__ cursor, const float* __restrict__ dinv,
    int* __restrict__ csr_col, float* __restrict__ csr_val) {
  int e = blockIdx.x * blockDim.x + threadIdx.x;
  if (e < NE) {
    int r = row[e], c = col[e];
    int pos = row_off[r] + atomicAdd(&cursor[r], 1);
    csr_col[pos] = c;
    csr_val[pos] = -dinv[r] * dinv[c];
  }
}

// ---------------- casts ----------------

// W[s][k][n] f32 -> Bt[n][s*512+k] bf16, via LDS 64x64 transpose tiles
__global__ __launch_bounds__(256) void k_wcast(const float* __restrict__ W, unsigned short* __restrict__ Bt) {
  __shared__ float sm[64][68];
  const int t = blockIdx.x;            // 0..511 : 8 slices * 64 tiles
  const int s = t >> 6;
  const int rem = t & 63;
  const int kt0 = (rem >> 3) * 64;
  const int nt0 = (rem & 7) * 64;
  const float* w = W + ((size_t)s << 18);
  const int tid = threadIdx.x;
  #pragma unroll
  for (int i = 0; i < 4; ++i) {
    int f = tid + i * 256;
    int r = f >> 4;
    int c4 = f & 15;
    float4 v = *(const float4*)&w[(size_t)(kt0 + r) * CC + nt0 + c4 * 4];
    sm[r][c4 * 4 + 0] = v.x; sm[r][c4 * 4 + 1] = v.y;
    sm[r][c4 * 4 + 2] = v.z; sm[r][c4 * 4 + 3] = v.w;
  }
  __syncthreads();
  #pragma unroll
  for (int i = 0; i < 2; ++i) {
    int g = tid + i * 256;
    int nl = g >> 3;
    int k8 = (g & 7) * 8;
    ushort8v o;
    #pragma unroll
    for (int j = 0; j < 8; ++j) o[j] = f2bf(sm[k8 + j][nl]);
    *(ushort8v*)&Bt[(size_t)(nt0 + nl) * KT + s * CC + kt0 + k8] = o;
  }
}

// x f32 -> TxAll slice 0 (row stride KT)
__global__ __launch_bounds__(256) void k_xcast(const float* __restrict__ x, unsigned short* __restrict__ txall) {
  size_t t = (size_t)blockIdx.x * 256 + threadIdx.x;
  size_t idx = t * 8;
  if (idx >= (size_t)NN * CC) return;
  size_t r = idx >> 9;
  int c = (int)(idx & 511);
  const float4* p = (const float4*)&x[idx];
  float4 a = p[0], b = p[1];
  ushort8v v;
  v[0] = f2bf(a.x); v[1] = f2bf(a.y); v[2] = f2bf(a.z); v[3] = f2bf(a.w);
  v[4] = f2bf(b.x); v[5] = f2bf(b.y); v[6] = f2bf(b.z); v[7] = f2bf(b.w);
  *(ushort8v*)&txall[r * KT + c] = v;
}

// ---------------- SPMM: dst = alpha*L*src + beta*prev ; writes bf16 slice into TxAll ----
// one block per node, 256 threads: 2-way edge split (es) x 128 channel-threads,
// each sub-lane unrolls x4 -> up to 8 gathers in flight per row.

__global__ __launch_bounds__(256) void k_spmm(const float* __restrict__ src,
    const float* __restrict__ prev, float* __restrict__ dst, unsigned short* __restrict__ abf,
    const int* __restrict__ row_off, const int* __restrict__ csr_col,
    const float* __restrict__ csr_val, float alpha, float beta, int wf32)
{
  __shared__ float4 smx[128];
  const int i = blockIdx.x;
  const int tid = threadIdx.x;
  const int es = tid >> 7;          // 0/1 : edge parity
  const int c = (tid & 127) * 4;    // channel offset
  const int e0 = row_off[i];
  const int e1 = row_off[i + 1];
  float4 a0 = make_float4(0.f,0.f,0.f,0.f), a1 = a0, a2 = a0, a3 = a0;
  int e = e0 + es;
  for (; e + 6 < e1; e += 8) {
    int j0 = csr_col[e], j1 = csr_col[e+2], j2 = csr_col[e+4], j3 = csr_col[e+6];
    float v0 = csr_val[e], v1 = csr_val[e+2], v2 = csr_val[e+4], v3 = csr_val[e+6];
    const float4 x0 = *(const float4*)&src[(size_t)j0 * CC + c];
    const float4 x1 = *(const float4*)&src[(size_t)j1 * CC + c];
    const float4 x2 = *(const float4*)&src[(size_t)j2 * CC + c];
    const float4 x3 = *(const float4*)&src[(size_t)j3 * CC + c];
    a0.x += v0*x0.x; a0.y += v0*x0.y; a0.z += v0*x0.z; a0.w += v0*x0.w;
    a1.x += v1*x1.x; a1.y += v1*x1.y; a1.z += v1*x1.z; a1.w += v1*x1.w;
    a2.x += v2*x2.x; a2.y += v2*x2.y; a2.z += v2*x2.z; a2.w += v2*x2.w;
    a3.x += v3*x3.x; a3.y += v3*x3.y; a3.z += v3*x3.z; a3.w += v3*x3.w;
  }
  for (; e < e1; e += 2) {
    int j = csr_col[e];
    float v = csr_val[e];
    const float4 xv = *(const float4*)&src[(size_t)j * CC + c];
    a0.x += v*xv.x; a0.y += v*xv.y; a0.z += v*xv.z; a0.w += v*xv.w;
  }
  float4 s;
  s.x = (a0.x + a1.x) + (a2.x + a3.x);
  s.y = (a0.y + a1.y) + (a2.y + a3.y);
  s.z = (a0.z + a1.z) + (a2.z + a3.z);
  s.w = (a0.w + a1.w) + (a2.w + a3.w);
  if (es == 1) smx[tid & 127] = s;
  __syncthreads();
  if (es == 0) {
    const float4 o = smx[tid];
    s.x += o.x; s.y += o.y; s.z += o.z; s.w += o.w;
    float4 r;
    if (beta != 0.0f) {
      const float4 p = *(const float4*)&prev[(size_t)i * CC + c];
      r.x = alpha * s.x + beta * p.x;
      r.y = alpha * s.y + beta * p.y;
      r.z = alpha * s.z + beta * p.z;
      r.w = alpha * s.w + beta * p.w;
    } else {
      r.x = alpha * s.x; r.y = alpha * s.y; r.z = alpha * s.z; r.w = alpha * s.w;
    }
    if (wf32) *(float4*)&dst[(size_t)i * CC + c] = r;
    ushort4v bv;
    bv[0] = f2bf(r.x); bv[1] = f2bf(r.y); bv[2] = f2bf(r.z); bv[3] = f2bf(r.w);
    *(ushort4v*)&abf[(size_t)i * KT + c] = bv;
  }
}

// ---------------- fused MFMA GEMM: C = TxAll[NP,4096] @ Bt[512,4096]^T + bias ----------
// 128x128 tile, BK=32, 2-phase double-buffered LDS: stage(t+1) issued BEFORE compute(t),
// single __syncthreads (implicit vmcnt(0)+lgkmcnt(0)) per K-step.

__global__ __launch_bounds__(256) void k_gemm(const unsigned short* __restrict__ A,
    const unsigned short* __restrict__ Bt, float* __restrict__ C,
    const float* __restrict__ bias)
{
  __shared__ unsigned short smA[2][128 * 32];
  __shared__ unsigned short smB[2][128 * 32];
  const int tid  = threadIdx.x;
  const int lane = tid & 63;
  const int wave = tid >> 6;
  const int wr = wave >> 1, wc = wave & 1;

  // bijective XCD swizzle over 628 workgroups (q=78, r=4)
  const int nwg = (NP / 128) * 4;
  int bid = blockIdx.x;
  int q = nwg >> 3, rr = nwg & 7;
  int xcd = bid & 7, lid = bid >> 3;
  int wgid = (xcd < rr ? xcd * (q + 1) : rr * (q + 1) + (xcd - rr) * q) + lid;
  const int m0 = (wgid >> 2) * 128;
  const int n0 = (wgid & 3) * 128;

  const int srow = lane >> 2;          // 0..15
  const int skc  = (lane & 3) * 8;     // k-offset in ushorts

  const unsigned short* Ab = &A[(size_t)(m0 + srow) * KT + skc];
  const unsigned short* Bb = &Bt[(size_t)(n0 + srow) * KT + skc];

  f32x4 acc[4][4] = {};

#define STAGE(K0, BUF)                                                          \
  {                                                                             \
    _Pragma("unroll")                                                           \
    for (int i_ = 0; i_ < 2; ++i_) {                                            \
      int rowb_ = wave * 32 + i_ * 16;                                          \
      gload_lds16(Ab + (size_t)rowb_ * KT + (K0), &smA[BUF][rowb_ * 32]);       \
      gload_lds16(Bb + (size_t)rowb_ * KT + (K0), &smB[BUF][rowb_ * 32]);       \
    }                                                                           \
  }

#define COMPUTE(BUF)                                                            \
  {                                                                             \
    short8 af_[4], bf_[4];                                                      \
    _Pragma("unroll")                                                           \
    for (int f_ = 0; f_ < 4; ++f_) {                                            \
      af_[f_] = *(const short8*)&smA[BUF][(wr * 64 + f_ * 16 + (lane & 15)) * 32 + (lane >> 4) * 8]; \
      bf_[f_] = *(const short8*)&smB[BUF][(wc * 64 + f_ * 16 + (lane & 15)) * 32 + (lane >> 4) * 8]; \
    }                                                                           \
    _Pragma("unroll")                                                           \
    for (int fm_ = 0; fm_ < 4; ++fm_)                                           \
      _Pragma("unroll")                                                         \
      for (int fn_ = 0; fn_ < 4; ++fn_)                                         \
        acc[fm_][fn_] = __builtin_amdgcn_mfma_f32_16x16x32_bf16(af_[fm_], bf_[fn_], acc[fm_][fn_], 0, 0, 0); \
  }

  STAGE(0, 0);
  __syncthreads();
  for (int k0 = 0; k0 < KT; k0 += 64) {
    STAGE(k0 + 32, 1);               // k0+32 < KT always (KT multiple of 64)
    COMPUTE(0);
    __syncthreads();
    if (k0 + 64 < KT) STAGE(k0 + 64, 0);
    COMPUTE(1);
    __syncthreads();
  }
#undef STAGE
#undef COMPUTE

  const int prow = (lane >> 4) * 4;
  const int pcol = lane & 15;
  #pragma unroll
  for (int fm = 0; fm < 4; ++fm) {
    #pragma unroll
    for (int fn = 0; fn < 4; ++fn) {
      int gcol = n0 + wc * 64 + fn * 16 + pcol;
      float bb = bias[gcol];
      #pragma unroll
      for (int j = 0; j < 4; ++j) {
        int grow = m0 + wr * 64 + fm * 16 + prow + j;
        if (grow < NN) C[(size_t)grow * CC + gcol] = acc[fm][fn][j] + bb;
      }
    }
  }
}

// ---------------- launch ----------------

extern "C" void kernel_launch(void* const* d_in, const int* in_sizes, int n_in,
                              void* d_out, int out_size, void* d_ws, size_t ws_size,
                              hipStream_t stream) {
  const float* x      = (const float*)d_in[0];
  const int*   row    = (const int*)d_in[1];
  const int*   col    = row + NE;
  const float* weight = (const float*)d_in[2];
  const float* bias   = (const float*)d_in[3];
  float* out = (float*)d_out;

  // workspace (~211 MB); d_out doubles as recurrence buffer TxB (GEMM overwrites it last)
  unsigned short* TxAll = (unsigned short*)d_ws;               // NP*KT bf16
  unsigned short* Bt    = TxAll + (size_t)NP * KT;             // 512*KT bf16
  float* TxA     = (float*)(Bt + (size_t)CC * KT);             // NN*CC f32
  float* dinv    = TxA + (size_t)NN * CC;
  float* csr_val = dinv + NN;
  int*   deg     = (int*)(csr_val + NE);
  int*   cursor  = deg + NN;
  int*   row_off = cursor + NN;
  int*   csr_col = row_off + NN + 1;
  int*   bsum    = csr_col + NE;
  float* TxB     = out;

  k_zero<<<(NN + 255) / 256, 256, 0, stream>>>(deg, cursor);
  k_count<<<(NE + 255) / 256, 256, 0, stream>>>(row, deg);
  k_dinv<<<(NN + 255) / 256, 256, 0, stream>>>(deg, dinv);
  k_scanA<<<SCB, 1024, 0, stream>>>(deg, row_off, bsum);
  k_scanB<<<1, 64, 0, stream>>>(bsum);
  k_scanC<<<SCB, 1024, 0, stream>>>(row_off, bsum);
  k_fill<<<(NE + 255) / 256, 256, 0, stream>>>(row, col, row_off, cursor, dinv, csr_col, csr_val);

  k_wcast<<<512, 256, 0, stream>>>(weight, Bt);
  k_xcast<<<(NN * CC / 8 + 255) / 256, 256, 0, stream>>>(x, TxAll);

  // Tx1 = L x          -> TxA, slice 1
  k_spmm<<<NN, 256, 0, stream>>>(x, x, TxA, TxAll + 1 * CC, row_off, csr_col, csr_val, 1.0f, 0.0f, 1);
  // Tx2 = 2 L Tx1 - x  -> TxB(out), slice 2
  k_spmm<<<NN, 256, 0, stream>>>(TxA, x, TxB, TxAll + 2 * CC, row_off, csr_col, csr_val, 2.0f, -1.0f, 1);
  // k = 3..7 ping-pong; last pass skips the dead f32 store
  float* bufs[2] = { TxA, TxB };
  for (int k = 3; k < KW; ++k) {
    float* dst = bufs[(k + 1) & 1];
    float* src = bufs[k & 1];
    k_spmm<<<NN, 256, 0, stream>>>(src, dst, dst, TxAll + (size_t)k * CC, row_off, csr_col, csr_val,
                                   2.0f, -1.0f, (k < KW - 1) ? 1 : 0);
  }

  // single fused GEMM: out = [Tx_0 | ... | Tx_7] @ [W_0; ...; W_7] + bias
  k_gemm<<<(NP / 128) * 4, 256, 0, stream>>>(TxAll, Bt, out, bias);
}

// Round 6
// 384.486 us; speedup vs baseline: 4.3949x; 1.4548x over previous
//
#include <hip/hip_runtime.h>

#define NN 20000
#define NP 20096   // M padded to multiple of 128
#define NE 150000
#define CC 512
#define KW 8
#define KT 4096    // KW*CC — fused GEMM K
#define SCB 20     // scan blocks: ceil(NN/1024)

typedef __attribute__((ext_vector_type(8))) short short8;
typedef __attribute__((ext_vector_type(4))) float f32x4;
typedef __attribute__((ext_vector_type(4))) unsigned short ushort4v;
typedef __attribute__((ext_vector_type(8))) unsigned short ushort8v;

__device__ inline unsigned short f2bf(float f) {   // RNE f32->bf16
  unsigned u = __builtin_bit_cast(unsigned, f);
  u += 0x7fffu + ((u >> 16) & 1u);
  return (unsigned short)(u >> 16);
}

__device__ inline float bf2f(unsigned short u) {
  return __builtin_bit_cast(float, (unsigned)u << 16);
}

__device__ inline void gload_lds16(const void* g, void* l) {
  __builtin_amdgcn_global_load_lds(
      (const __attribute__((address_space(1))) unsigned int*)g,
      (__attribute__((address_space(3))) unsigned int*)l, 16, 0, 0);
}

// ---------------- setup kernels ----------------

__global__ __launch_bounds__(256) void k_zero(int* __restrict__ deg, int* __restrict__ cursor) {
  int i = blockIdx.x * blockDim.x + threadIdx.x;
  if (i < NN) { deg[i] = 0; cursor[i] = 0; }
}

__global__ __launch_bounds__(256) void k_count(const int* __restrict__ row, int* __restrict__ deg) {
  int e = blockIdx.x * blockDim.x + threadIdx.x;
  if (e < NE) atomicAdd(&deg[row[e]], 1);
}

__global__ __launch_bounds__(256) void k_dinv(const int* __restrict__ deg, float* __restrict__ dinv) {
  int i = blockIdx.x * blockDim.x + threadIdx.x;
  if (i < NN) {
    int d = deg[i];
    dinv[i] = (d > 0) ? rsqrtf((float)d) : 0.0f;
  }
}

// hierarchical scan: A) per-block 1024 scan, B) scan of 20 block sums, C) add offsets
__global__ __launch_bounds__(1024) void k_scanA(const int* __restrict__ deg,
    int* __restrict__ row_off, int* __restrict__ bsum) {
  __shared__ int sm[1024];
  const int b = blockIdx.x, tid = threadIdx.x;
  int i = b * 1024 + tid;
  int v = (i < NN) ? deg[i] : 0;
  sm[tid] = v;
  __syncthreads();
  #pragma unroll
  for (int off = 1; off < 1024; off <<= 1) {
    int t = (tid >= off) ? sm[tid - off] : 0;
    __syncthreads();
    if (tid >= off) sm[tid] += t;
    __syncthreads();
  }
  if (i < NN) row_off[i] = sm[tid] - v;
  if (tid == 1023) bsum[b] = sm[1023];
}

__global__ __launch_bounds__(64) void k_scanB(int* __restrict__ bsum) {
  if (threadIdx.x == 0) {
    int run = 0;
    for (int b = 0; b < SCB; ++b) { int t = bsum[b]; bsum[b] = run; run += t; }
  }
}

__global__ __launch_bounds__(1024) void k_scanC(int* __restrict__ row_off, const int* __restrict__ bsum) {
  int i = blockIdx.x * 1024 + threadIdx.x;
  if (i < NN) row_off[i] += bsum[blockIdx.x];
  if (i == NN - 1) row_off[NN] = NE;
}

__global__ __launch_bounds__(256) void k_fill(const int* __restrict__ row, const int* __restrict__ col,
    const int* __restrict__ row_off, int* __restrict__ cursor, const float* __restrict__ dinv,
    int* __restrict__ csr_col, float* __restrict__ csr_val) {
  int e = blockIdx.x * blockDim.x + threadIdx.x;
  if (e < NE) {
    int r = row[e], c = col[e];
    int pos = row_off[r] + atomicAdd(&cursor[r], 1);
    csr_col[pos] = c;
    csr_val[pos] = -dinv[r] * dinv[c];
  }
}

// ---------------- casts ----------------

// W[s][k][n] f32 -> Bt[n][s*512+k] bf16, via LDS 64x64 transpose tiles
__global__ __launch_bounds__(256) void k_wcast(const float* __restrict__ W, unsigned short* __restrict__ Bt) {
  __shared__ float sm[64][68];
  const int t = blockIdx.x;            // 0..511 : 8 slices * 64 tiles
  const int s = t >> 6;
  const int rem = t & 63;
  const int kt0 = (rem >> 3) * 64;
  const int nt0 = (rem & 7) * 64;
  const float* w = W + ((size_t)s << 18);
  const int tid = threadIdx.x;
  #pragma unroll
  for (int i = 0; i < 4; ++i) {
    int f = tid + i * 256;
    int r = f >> 4;
    int c4 = f & 15;
    float4 v = *(const float4*)&w[(size_t)(kt0 + r) * CC + nt0 + c4 * 4];
    sm[r][c4 * 4 + 0] = v.x; sm[r][c4 * 4 + 1] = v.y;
    sm[r][c4 * 4 + 2] = v.z; sm[r][c4 * 4 + 3] = v.w;
  }
  __syncthreads();
  #pragma unroll
  for (int i = 0; i < 2; ++i) {
    int g = tid + i * 256;
    int nl = g >> 3;
    int k8 = (g & 7) * 8;
    ushort8v o;
    #pragma unroll
    for (int j = 0; j < 8; ++j) o[j] = f2bf(sm[k8 + j][nl]);
    *(ushort8v*)&Bt[(size_t)(nt0 + nl) * KT + s * CC + kt0 + k8] = o;
  }
}

// x f32 -> TxAll slice 0 (row stride KT)
__global__ __launch_bounds__(256) void k_xcast(const float* __restrict__ x, unsigned short* __restrict__ txall) {
  size_t t = (size_t)blockIdx.x * 256 + threadIdx.x;
  size_t idx = t * 8;
  if (idx >= (size_t)NN * CC) return;
  size_t r = idx >> 9;
  int c = (int)(idx & 511);
  const float4* p = (const float4*)&x[idx];
  float4 a = p[0], b = p[1];
  ushort8v v;
  v[0] = f2bf(a.x); v[1] = f2bf(a.y); v[2] = f2bf(a.z); v[3] = f2bf(a.w);
  v[4] = f2bf(b.x); v[5] = f2bf(b.y); v[6] = f2bf(b.z); v[7] = f2bf(b.w);
  *(ushort8v*)&txall[r * KT + c] = v;
}

// ---------------- SPMM (all-bf16): slice_k = alpha * L * slice_{k-1} + beta * slice_{k-2} ----
// Buffers are bf16 slices inside TxAll (row stride KT). f32 accumulation in-register.
// one block per node, 256 threads: 2-way edge split (es) x 128 channel-threads, x4 unroll.

__global__ __launch_bounds__(256) void k_spmm(const unsigned short* __restrict__ gsrc,
    const unsigned short* __restrict__ gprev, unsigned short* __restrict__ gdst,
    const int* __restrict__ row_off, const int* __restrict__ csr_col,
    const float* __restrict__ csr_val, float alpha, float beta)
{
  __shared__ float4 smx[128];
  const int i = blockIdx.x;
  const int tid = threadIdx.x;
  const int es = tid >> 7;          // 0/1 : edge parity
  const int c = (tid & 127) * 4;    // channel offset (ushorts)
  const int e0 = row_off[i];
  const int e1 = row_off[i + 1];
  float4 a0 = make_float4(0.f,0.f,0.f,0.f), a1 = a0, a2 = a0, a3 = a0;
  int e = e0 + es;
  for (; e + 6 < e1; e += 8) {
    int j0 = csr_col[e], j1 = csr_col[e+2], j2 = csr_col[e+4], j3 = csr_col[e+6];
    float v0 = csr_val[e], v1 = csr_val[e+2], v2 = csr_val[e+4], v3 = csr_val[e+6];
    const ushort4v x0 = *(const ushort4v*)&gsrc[(size_t)j0 * KT + c];
    const ushort4v x1 = *(const ushort4v*)&gsrc[(size_t)j1 * KT + c];
    const ushort4v x2 = *(const ushort4v*)&gsrc[(size_t)j2 * KT + c];
    const ushort4v x3 = *(const ushort4v*)&gsrc[(size_t)j3 * KT + c];
    a0.x += v0*bf2f(x0[0]); a0.y += v0*bf2f(x0[1]); a0.z += v0*bf2f(x0[2]); a0.w += v0*bf2f(x0[3]);
    a1.x += v1*bf2f(x1[0]); a1.y += v1*bf2f(x1[1]); a1.z += v1*bf2f(x1[2]); a1.w += v1*bf2f(x1[3]);
    a2.x += v2*bf2f(x2[0]); a2.y += v2*bf2f(x2[1]); a2.z += v2*bf2f(x2[2]); a2.w += v2*bf2f(x2[3]);
    a3.x += v3*bf2f(x3[0]); a3.y += v3*bf2f(x3[1]); a3.z += v3*bf2f(x3[2]); a3.w += v3*bf2f(x3[3]);
  }
  for (; e < e1; e += 2) {
    int j = csr_col[e];
    float v = csr_val[e];
    const ushort4v xv = *(const ushort4v*)&gsrc[(size_t)j * KT + c];
    a0.x += v*bf2f(xv[0]); a0.y += v*bf2f(xv[1]); a0.z += v*bf2f(xv[2]); a0.w += v*bf2f(xv[3]);
  }
  float4 s;
  s.x = (a0.x + a1.x) + (a2.x + a3.x);
  s.y = (a0.y + a1.y) + (a2.y + a3.y);
  s.z = (a0.z + a1.z) + (a2.z + a3.z);
  s.w = (a0.w + a1.w) + (a2.w + a3.w);
  if (es == 1) smx[tid & 127] = s;
  __syncthreads();
  if (es == 0) {
    const float4 o = smx[tid];
    s.x += o.x; s.y += o.y; s.z += o.z; s.w += o.w;
    float4 r;
    if (beta != 0.0f) {
      const ushort4v p = *(const ushort4v*)&gprev[(size_t)i * KT + c];
      r.x = alpha * s.x + beta * bf2f(p[0]);
      r.y = alpha * s.y + beta * bf2f(p[1]);
      r.z = alpha * s.z + beta * bf2f(p[2]);
      r.w = alpha * s.w + beta * bf2f(p[3]);
    } else {
      r.x = alpha * s.x; r.y = alpha * s.y; r.z = alpha * s.z; r.w = alpha * s.w;
    }
    ushort4v bv;
    bv[0] = f2bf(r.x); bv[1] = f2bf(r.y); bv[2] = f2bf(r.z); bv[3] = f2bf(r.w);
    *(ushort4v*)&gdst[(size_t)i * KT + c] = bv;
  }
}

// ---------------- fused MFMA GEMM: C = TxAll[NP,4096] @ Bt[512,4096]^T + bias ----------
// 128x128 tile, BK=32, single-buffer (round-3 form: fastest measured at this grid).

__global__ __launch_bounds__(256) void k_gemm(const unsigned short* __restrict__ A,
    const unsigned short* __restrict__ Bt, float* __restrict__ C,
    const float* __restrict__ bias)
{
  __shared__ unsigned short smA[128 * 32];
  __shared__ unsigned short smB[128 * 32];
  const int tid  = threadIdx.x;
  const int lane = tid & 63;
  const int wave = tid >> 6;
  const int wr = wave >> 1, wc = wave & 1;

  // bijective XCD swizzle over 628 workgroups
  const int nwg = (NP / 128) * 4;
  int bid = blockIdx.x;
  int q = nwg >> 3, rr = nwg & 7;
  int xcd = bid & 7, lid = bid >> 3;
  int wgid = (xcd < rr ? xcd * (q + 1) : rr * (q + 1) + (xcd - rr) * q) + lid;
  const int m0 = (wgid >> 2) * 128;
  const int n0 = (wgid & 3) * 128;

  const int srow = lane >> 2;
  const int skc  = (lane & 3) * 8;

  f32x4 acc[4][4] = {};

  for (int k0 = 0; k0 < KT; k0 += 32) {
    #pragma unroll
    for (int i = 0; i < 2; ++i) {
      int row = wave * 32 + i * 16;
      gload_lds16(&A[(size_t)(m0 + row + srow) * KT + k0 + skc], &smA[row * 32]);
      gload_lds16(&Bt[(size_t)(n0 + row + srow) * KT + k0 + skc], &smB[row * 32]);
    }
    __syncthreads();

    short8 af[4], bfv[4];
    #pragma unroll
    for (int f = 0; f < 4; ++f) {
      af[f]  = *(const short8*)&smA[(wr * 64 + f * 16 + (lane & 15)) * 32 + (lane >> 4) * 8];
      bfv[f] = *(const short8*)&smB[(wc * 64 + f * 16 + (lane & 15)) * 32 + (lane >> 4) * 8];
    }
    #pragma unroll
    for (int fm = 0; fm < 4; ++fm)
      #pragma unroll
      for (int fn = 0; fn < 4; ++fn)
        acc[fm][fn] = __builtin_amdgcn_mfma_f32_16x16x32_bf16(af[fm], bfv[fn], acc[fm][fn], 0, 0, 0);
    __syncthreads();
  }

  const int prow = (lane >> 4) * 4;
  const int pcol = lane & 15;
  #pragma unroll
  for (int fm = 0; fm < 4; ++fm) {
    #pragma unroll
    for (int fn = 0; fn < 4; ++fn) {
      int gcol = n0 + wc * 64 + fn * 16 + pcol;
      float bb = bias[gcol];
      #pragma unroll
      for (int j = 0; j < 4; ++j) {
        int grow = m0 + wr * 64 + fm * 16 + prow + j;
        if (grow < NN) C[(size_t)grow * CC + gcol] = acc[fm][fn][j] + bb;
      }
    }
  }
}

// ---------------- launch ----------------

extern "C" void kernel_launch(void* const* d_in, const int* in_sizes, int n_in,
                              void* d_out, int out_size, void* d_ws, size_t ws_size,
                              hipStream_t stream) {
  const float* x      = (const float*)d_in[0];
  const int*   row    = (const int*)d_in[1];
  const int*   col    = row + NE;
  const float* weight = (const float*)d_in[2];
  const float* bias   = (const float*)d_in[3];
  float* out = (float*)d_out;

  // workspace (~170 MB): all recurrence state lives as bf16 slices in TxAll
  unsigned short* TxAll = (unsigned short*)d_ws;               // NP*KT bf16
  unsigned short* Bt    = TxAll + (size_t)NP * KT;             // 512*KT bf16
  float* dinv    = (float*)(Bt + (size_t)CC * KT);
  float* csr_val = dinv + NN;
  int*   deg     = (int*)(csr_val + NE);
  int*   cursor  = deg + NN;
  int*   row_off = cursor + NN;
  int*   csr_col = row_off + NN + 1;
  int*   bsum    = csr_col + NE;

  k_zero<<<(NN + 255) / 256, 256, 0, stream>>>(deg, cursor);
  k_count<<<(NE + 255) / 256, 256, 0, stream>>>(row, deg);
  k_dinv<<<(NN + 255) / 256, 256, 0, stream>>>(deg, dinv);
  k_scanA<<<SCB, 1024, 0, stream>>>(deg, row_off, bsum);
  k_scanB<<<1, 64, 0, stream>>>(bsum);
  k_scanC<<<SCB, 1024, 0, stream>>>(row_off, bsum);
  k_fill<<<(NE + 255) / 256, 256, 0, stream>>>(row, col, row_off, cursor, dinv, csr_col, csr_val);

  k_wcast<<<512, 256, 0, stream>>>(weight, Bt);
  k_xcast<<<(NN * CC / 8 + 255) / 256, 256, 0, stream>>>(x, TxAll);

  // Tx1 = L x  (slice0 -> slice1)
  k_spmm<<<NN, 256, 0, stream>>>(TxAll, TxAll, TxAll + CC, row_off, csr_col, csr_val, 1.0f, 0.0f);
  // Tx_k = 2 L Tx_{k-1} - Tx_{k-2}  (slices k-1, k-2 -> slice k)
  for (int k = 2; k < KW; ++k)
    k_spmm<<<NN, 256, 0, stream>>>(TxAll + (size_t)(k - 1) * CC, TxAll + (size_t)(k - 2) * CC,
                                   TxAll + (size_t)k * CC, row_off, csr_col, csr_val, 2.0f, -1.0f);

  // single fused GEMM: out = [Tx_0 | ... | Tx_7] @ [W_0; ...; W_7] + bias
  k_gemm<<<(NP / 128) * 4, 256, 0, stream>>>(TxAll, Bt, out, bias);
}